// Round 1
// baseline (1823.585 us; speedup 1.0000x reference)
//
#include <hip/hip_runtime.h>
#include <stdint.h>

#define NIMG 8
#define HFW  64
#define HWA  36864     // 64*64*9
#define PRE  2000
#define POST 300
#define LISTN 2048

__device__ __forceinline__ unsigned keyOf(float f) {
    unsigned u = __float_as_uint(f);
    return (u & 0x80000000u) ? ~u : (u | 0x80000000u);
}
__device__ __forceinline__ unsigned umin2(unsigned a, unsigned b){ return a < b ? a : b; }

// ---------------------------------------------------------------------------
// K0: transform w_conv [co][ci][3][3] -> wt [ci][ky][co][4] (kx padded to 4)
// ---------------------------------------------------------------------------
__global__ void prep_wt(const float* __restrict__ w, float* __restrict__ wt) {
    int t = blockIdx.x * 256 + threadIdx.x;      // t = (ci*3+ky)*256 + co
    if (t >= 256 * 3 * 256) return;
    int co = t & 255;
    int r  = t >> 8;            // ci*3+ky
    int ky = r % 3, ci = r / 3;
    const float* s = w + ((size_t)(co * 256 + ci)) * 9 + ky * 3;
    float4 v; v.x = s[0]; v.y = s[1]; v.z = s[2]; v.w = 0.0f;
    *(float4*)&wt[(size_t)t * 4] = v;
}

// ---------------------------------------------------------------------------
// K1: 3x3 conv SAME + bias + relu.  fp32, VALU.
// block 128 thr; tile: 128 co x 64 px (one y row); thread: 8co x 8px.
// grid (2 co-groups, 64 y, 8 n)
// ---------------------------------------------------------------------------
#define CK 4
__global__ __launch_bounds__(128) void conv3x3_relu(const float* __restrict__ feat,
        const float* __restrict__ wt, const float* __restrict__ bconv,
        float* __restrict__ h)
{
    __shared__ float sF[CK][3][72];          // [ci][ky][x+4], zeros at 3 and 68
    __shared__ float sW[CK][3][128][4];      // co slot XOR-swizzled

    const int tid = threadIdx.x;
    const int cog = blockIdx.x;   // 0..1
    const int y   = blockIdx.y;   // 0..63
    const int n   = blockIdx.z;   // 0..7
    const int px0 = (tid & 7) * 8;
    const int cot = tid >> 3;     // 0..15
    const int m   = cot & 7;

    float acc[8][8];
#pragma unroll
    for (int a = 0; a < 8; a++)
#pragma unroll
        for (int b = 0; b < 8; b++) acc[a][b] = 0.0f;

    const float* fb2 = feat + (size_t)n * 1048576;  // n*256*4096

    for (int ck = 0; ck < 64; ck++) {
        const int ci0 = ck * CK;
        // ---- stage weights: thread handles logical co_l = tid, swizzled slot
        {
            const int co_l = tid;
            const int q = co_l ^ ((co_l >> 3) & 7);
#pragma unroll
            for (int r = 0; r < 12; r++) {
                const int i = r / 3, ky = r % 3;
                const size_t gofs = (((size_t)(ci0 + i) * 3 + ky) * 256 + cog * 128 + co_l) * 4;
                float4 v = *(const float4*)&wt[gofs];
                *(float4*)&sW[i][ky][q][0] = v;
            }
        }
        // ---- stage features (192 float4 tasks)
        for (int task = tid; task < 192; task += 128) {
            const int r = task >> 4;            // 0..11
            const int i = r / 3, ky = r % 3;
            const int x4 = (task & 15) << 2;
            const int yy = y + ky - 1;
            float4 v = {0.f, 0.f, 0.f, 0.f};
            if (yy >= 0 && yy < 64)
                v = *(const float4*)(fb2 + (size_t)(ci0 + i) * 4096 + yy * 64 + x4);
            *(float4*)&sF[i][ky][4 + x4] = v;
        }
        if (tid < 12) {
            const int i = tid / 3, ky = tid % 3;
            sF[i][ky][3]  = 0.0f;
            sF[i][ky][68] = 0.0f;
        }
        __syncthreads();

        // ---- compute
#pragma unroll
        for (int i = 0; i < CK; i++)
#pragma unroll
        for (int ky = 0; ky < 3; ky++) {
            const float* fr = &sF[i][ky][0];
            float W[10];
            W[0] = fr[px0 + 3];
            float4 fa = *(const float4*)(fr + px0 + 4);
            float4 fbv = *(const float4*)(fr + px0 + 8);
            W[1]=fa.x; W[2]=fa.y; W[3]=fa.z; W[4]=fa.w;
            W[5]=fbv.x; W[6]=fbv.y; W[7]=fbv.z; W[8]=fbv.w;
            W[9] = fr[px0 + 12];
#pragma unroll
            for (int cc = 0; cc < 8; cc++) {
                float4 wv = *(const float4*)&sW[i][ky][(cot << 3) + (cc ^ m)][0];
#pragma unroll
                for (int p = 0; p < 8; p++) {
                    acc[cc][p] = fmaf(wv.x, W[p],     acc[cc][p]);
                    acc[cc][p] = fmaf(wv.y, W[p + 1], acc[cc][p]);
                    acc[cc][p] = fmaf(wv.z, W[p + 2], acc[cc][p]);
                }
            }
        }
        __syncthreads();
    }

    // ---- epilogue: bias + relu, store
#pragma unroll
    for (int cc = 0; cc < 8; cc++) {
        const int co = cog * 128 + (cot << 3) + cc;
        const float b = bconv[co];
        float4 o0, o1;
        o0.x = fmaxf(acc[cc][0] + b, 0.f); o0.y = fmaxf(acc[cc][1] + b, 0.f);
        o0.z = fmaxf(acc[cc][2] + b, 0.f); o0.w = fmaxf(acc[cc][3] + b, 0.f);
        o1.x = fmaxf(acc[cc][4] + b, 0.f); o1.y = fmaxf(acc[cc][5] + b, 0.f);
        o1.z = fmaxf(acc[cc][6] + b, 0.f); o1.w = fmaxf(acc[cc][7] + b, 0.f);
        float* hp = h + ((size_t)(n * 256 + co)) * 4096 + y * 64 + px0;
        *(float4*)hp       = o0;
        *(float4*)(hp + 4) = o1;
    }
}

// ---------------------------------------------------------------------------
// K2: 1x1 heads (scores 9, locs 36) + box decode + clip + validity -> keys/rois
// block 256, grid (64 y, 8 n)
// ---------------------------------------------------------------------------
__global__ __launch_bounds__(256) void head_decode(const float* __restrict__ h,
        const float* __restrict__ wsc, const float* __restrict__ bsc,
        const float* __restrict__ wlc, const float* __restrict__ blc,
        unsigned* __restrict__ keys, float* __restrict__ rois)
{
    __shared__ float sH[128][64];
    __shared__ float sOut[64][49];

    const int tid = threadIdx.x;
    const int y   = blockIdx.x;
    const int n   = blockIdx.y;
    const int px  = tid & 63;
    const int sl  = tid >> 6;             // == wave id
    const int o0  = sl * 12;

    const float* wp[12];
#pragma unroll
    for (int j = 0; j < 12; j++) {
        const int o = o0 + j;
        wp[j] = (o < 36) ? (wlc + (size_t)o * 256)
                         : ((o < 45) ? (wsc + (size_t)(o - 36) * 256) : wsc);
    }
    float r[12];
#pragma unroll
    for (int j = 0; j < 12; j++) r[j] = 0.0f;

    const float* hb = h + (size_t)n * 1048576 + y * 64;
    for (int half = 0; half < 2; half++) {
        for (int task = tid; task < 2048; task += 256) {
            const int c = task >> 4, x4 = (task & 15) << 2;
            *(float4*)&sH[c][x4] =
                *(const float4*)(hb + (size_t)(half * 128 + c) * 4096 + x4);
        }
        __syncthreads();
        for (int c4 = 0; c4 < 128; c4 += 4) {
            const float h0 = sH[c4][px], h1 = sH[c4 + 1][px];
            const float h2 = sH[c4 + 2][px], h3 = sH[c4 + 3][px];
#pragma unroll
            for (int j = 0; j < 12; j++) {
                float4 w = *(const float4*)(wp[j] + half * 128 + c4);
                r[j] = fmaf(h0, w.x, r[j]); r[j] = fmaf(h1, w.y, r[j]);
                r[j] = fmaf(h2, w.z, r[j]); r[j] = fmaf(h3, w.w, r[j]);
            }
        }
        __syncthreads();
    }
#pragma unroll
    for (int j = 0; j < 12; j++) {
        const int o = o0 + j;
        if (o < 45) {
            const float bias = (o < 36) ? blc[o] : bsc[o - 36];
            sOut[px][o] = r[j] + bias;
        }
    }
    __syncthreads();

    // decode (replicate reference fp32 op order; no contraction)
    for (int a = sl; a < 9; a += 4) {
        const float s  = sOut[px][36 + a];
        const float dy = sOut[px][a * 4 + 0], dx = sOut[px][a * 4 + 1];
        const float dh = sOut[px][a * 4 + 2], dw = sOut[px][a * 4 + 3];
        const int si = a / 3, ri = a - si * 3;
        const float scale = (si == 0) ? 64.f : ((si == 1) ? 128.f : 256.f);
        const float rat   = (ri == 0) ? 0.5f : ((ri == 1) ? 1.f : 2.f);
        const float sq = __fsqrt_rn(rat);
        const float hs = __fmul_rn(scale, sq);
        const float ws = __fdiv_rn(scale, sq);
        const float cy = (y  + 0.5f) * 16.0f;   // exact
        const float cx = (px + 0.5f) * 16.0f;
        const float y1 = __fsub_rn(cy, __fmul_rn(hs, 0.5f));
        const float x1 = __fsub_rn(cx, __fmul_rn(ws, 0.5f));
        const float y2 = __fadd_rn(cy, __fmul_rn(hs, 0.5f));
        const float x2 = __fadd_rn(cx, __fmul_rn(ws, 0.5f));
        const float ah = __fsub_rn(y2, y1), aw = __fsub_rn(x2, x1);
        const float acy = __fadd_rn(y1, __fmul_rn(0.5f, ah));
        const float acx = __fadd_rn(x1, __fmul_rn(0.5f, aw));
        const float pcy = __fadd_rn(__fmul_rn(dy, ah), acy);
        const float pcx = __fadd_rn(__fmul_rn(dx, aw), acx);
        const float ph  = __fmul_rn(expf(dh), ah);
        const float pw  = __fmul_rn(expf(dw), aw);
        float by1 = __fsub_rn(pcy, __fmul_rn(0.5f, ph));
        float bx1 = __fsub_rn(pcx, __fmul_rn(0.5f, pw));
        float by2 = __fadd_rn(pcy, __fmul_rn(0.5f, ph));
        float bx2 = __fadd_rn(pcx, __fmul_rn(0.5f, pw));
        by1 = fminf(fmaxf(by1, 0.f), 1024.f); by2 = fminf(fmaxf(by2, 0.f), 1024.f);
        bx1 = fminf(fmaxf(bx1, 0.f), 1024.f); bx2 = fminf(fmaxf(bx2, 0.f), 1024.f);
        const float bh = __fsub_rn(by2, by1), bw = __fsub_rn(bx2, bx1);
        const bool valid = (bh >= 16.f) && (bw >= 16.f) && (s >= 0.f);
        const float sm = valid ? s : -1e9f;
        const int idx = (y * 64 + px) * 9 + a;
        keys[(size_t)n * HWA + idx] = keyOf(sm);
        float4 bxv = {by1, bx1, by2, bx2};
        *(float4*)&rois[((size_t)n * HWA + idx) * 4] = bxv;
    }
}

// ---------------------------------------------------------------------------
// K3: exact top-2000 sorted (key desc, idx asc) via 3-level histogram select
//     + compaction + 2048 bitonic sort.  1 block (1024 thr) per image.
// ---------------------------------------------------------------------------
__global__ __launch_bounds__(1024) void topk_sort(const unsigned* __restrict__ keys,
        const float* __restrict__ rois, float* __restrict__ bk,
        unsigned* __restrict__ tkey)
{
    __shared__ unsigned long long s64[2048];     // 16 KB, aliased as 2x u32[2048]
    __shared__ unsigned sc[2];
    __shared__ unsigned cntG, cntE;
    unsigned* histA = (unsigned*)&s64[0];
    unsigned* histB = histA + 2048;

    const int tid = threadIdx.x;
    const int n   = blockIdx.x;
    const unsigned* kp = keys + (size_t)n * HWA;

    unsigned need = PRE;
    unsigned b1 = 0, b2 = 0;

    for (int lvl = 0; lvl < 3; lvl++) {
        for (int i = tid; i < 2048; i += 1024) histA[i] = 0u;
        if (tid == 0) { cntG = 0u; cntE = 0u; }
        __syncthreads();
        for (int i = tid; i < HWA; i += 1024) {
            const unsigned k = kp[i];
            bool sel; unsigned bucket;
            if (lvl == 0)      { sel = true;                           bucket = k >> 21; }
            else if (lvl == 1) { sel = (k >> 21) == b1;                bucket = (k >> 10) & 2047u; }
            else               { sel = (k >> 10) == ((b1 << 11) | b2); bucket = k & 1023u; }
            if (sel) atomicAdd(&histA[bucket], 1u);
        }
        __syncthreads();
        unsigned *src = histA, *dst = histB;
        for (int ofs = 1; ofs < 2048; ofs <<= 1) {
            for (int i = tid; i < 2048; i += 1024)
                dst[i] = src[i] + ((i + ofs) < 2048 ? src[i + ofs] : 0u);
            __syncthreads();
            unsigned* t = src; src = dst; dst = t;
        }
        for (int i = tid; i < 2048; i += 1024) {
            const unsigned s = src[i];
            const unsigned sn = (i < 2047) ? src[i + 1] : 0u;
            if (s >= need && sn < need) { sc[0] = (unsigned)i; sc[1] = sn; }
        }
        __syncthreads();
        const unsigned b = sc[0];
        need -= sc[1];
        if (lvl == 0) b1 = b; else if (lvl == 1) b2 = b;
        else {
            // done: T known
            const unsigned T = (b1 << 21) | (b2 << 10) | b;
            const unsigned G = PRE - need;    // count strictly greater than T
            __syncthreads();
            for (int i = tid; i < 2048; i += 1024) s64[i] = 0ull;
            __syncthreads();
            for (int i = tid; i < HWA; i += 1024) {
                const unsigned k = kp[i];
                if (k > T) {
                    const unsigned p = atomicAdd(&cntG, 1u);
                    s64[p] = ((unsigned long long)k << 32) | (unsigned)(~(unsigned)i);
                } else if (k == T) {
                    const unsigned p = atomicAdd(&cntE, 1u);
                    if (G + p < 2048u)
                        s64[G + p] = ((unsigned long long)k << 32) | (unsigned)(~(unsigned)i);
                }
            }
            __syncthreads();
            // bitonic sort, descending; ties (equal key) -> ~idx desc -> idx asc
            for (unsigned ksz = 2; ksz <= 2048; ksz <<= 1) {
                for (unsigned jst = ksz >> 1; jst > 0; jst >>= 1) {
                    const unsigned i = (unsigned)tid;
                    const unsigned low = i & (jst - 1);
                    const unsigned l = ((i ^ low) << 1) | low;
                    const unsigned pr = l | jst;
                    const unsigned long long va = s64[l], vb = s64[pr];
                    const bool desc = (l & ksz) == 0;
                    if ((va < vb) == desc) { s64[l] = vb; s64[pr] = va; }
                    __syncthreads();
                }
            }
            const unsigned KEYNEG = ~__float_as_uint(-1e9f);
            for (int j = tid; j < 2048; j += 1024) {
                const unsigned long long v = s64[j];
                const unsigned key = (unsigned)(v >> 32);
                const unsigned idx = ~(unsigned)(v & 0xFFFFFFFFull);
                float4 box = {0.f, 0.f, 0.f, 0.f};
                if (key > KEYNEG) box = *(const float4*)&rois[((size_t)n * HWA + idx) * 4];
                *(float4*)&bk[((size_t)n * 2048 + j) * 4] = box;
                tkey[(size_t)n * 2048 + j] = (j < PRE) ? key : 0u;
            }
            return;
        }
        __syncthreads();
    }
}

// ---------------------------------------------------------------------------
// K4: greedy NMS (list is score-sorted: argmax(live)==first live) + output.
//     1 block (256 thr) per image; boxes + live flags in LDS.
// ---------------------------------------------------------------------------
__global__ __launch_bounds__(256) void nms_out(const float* __restrict__ bk,
        const unsigned* __restrict__ tkey, float* __restrict__ out)
{
    __shared__ float sy1[2048], sx1[2048], sy2[2048], sx2[2048];
    __shared__ unsigned lv[2048];
    __shared__ unsigned sRed[4];

    const int tid = threadIdx.x;
    const int n   = blockIdx.x;
    const unsigned KEYNEG = ~__float_as_uint(-1e9f);

    for (int i = tid; i < 2048; i += 256) {
        float4 b = *(const float4*)&bk[((size_t)n * 2048 + i) * 4];
        sy1[i] = b.x; sx1[i] = b.y; sy2[i] = b.z; sx2[i] = b.w;
        lv[i] = (i < PRE) && (tkey[(size_t)n * 2048 + i] > KEYNEG);
    }
    if (n == 0 && tid == 0) out[9600] = 0.0f;   // rpn_loss
    __syncthreads();

    for (int it = 0; it < POST; it++) {
        unsigned cand = 0xFFFFFFFFu;
#pragma unroll
        for (int q = 0; q < 8; q++) {
            const int k = q * 256 + tid;         // stride-256: conflict-free
            if (lv[k]) cand = umin2(cand, (unsigned)k);
        }
#pragma unroll
        for (int off = 32; off; off >>= 1)
            cand = umin2(cand, (unsigned)__shfl_xor((int)cand, off, 64));
        if ((tid & 63) == 0) sRed[tid >> 6] = cand;
        __syncthreads();
        const unsigned j = umin2(umin2(sRed[0], sRed[1]), umin2(sRed[2], sRed[3]));

        float4 ob = {0.f, 0.f, 0.f, 0.f};
        if (j != 0xFFFFFFFFu) {
            const float jy1 = sy1[j], jx1 = sx1[j], jy2 = sy2[j], jx2 = sx2[j];
            const float a1 = (jy2 - jy1) * (jx2 - jx1);
#pragma unroll
            for (int q = 0; q < 8; q++) {
                const int k = q * 256 + tid;
                if (lv[k]) {
                    const float ty = fmaxf(jy1, sy1[k]), tx = fmaxf(jx1, sx1[k]);
                    const float by = fminf(jy2, sy2[k]), bx = fminf(jx2, sx2[k]);
                    const float ih = fmaxf(by - ty, 0.f), iw = fmaxf(bx - tx, 0.f);
                    const float inter = ih * iw;
                    const float a2 = (sy2[k] - sy1[k]) * (sx2[k] - sx1[k]);
                    const float iou = inter / ((a1 + a2) - inter);  // exact fp32 div
                    if (iou > 0.7f) lv[k] = 0u;   // suppresses j itself too (iou=1)
                }
            }
            ob = make_float4(jy1, jx1, jy2, jx2);
        }
        if (tid == 0) *(float4*)&out[((size_t)n * POST + it) * 4] = ob;
        __syncthreads();   // lv updates visible before next scan
    }
}

// ---------------------------------------------------------------------------
extern "C" void kernel_launch(void* const* d_in, const int* in_sizes, int n_in,
                              void* d_out, int out_size, void* d_ws, size_t ws_size,
                              hipStream_t stream)
{
    // d_in: 0=images(unused) 1=features 2=w_conv 3=b_conv 4=w_score 5=b_score 6=w_loc 7=b_loc
    const float* feat  = (const float*)d_in[1];
    const float* wconv = (const float*)d_in[2];
    const float* bconv = (const float*)d_in[3];
    const float* wsc   = (const float*)d_in[4];
    const float* bsc   = (const float*)d_in[5];
    const float* wlc   = (const float*)d_in[6];
    const float* blc   = (const float*)d_in[7];
    float* out = (float*)d_out;

    char* ws = (char*)d_ws;
    float*    h    = (float*)(ws);                   // 33,554,432 B
    float*    wt   = (float*)(ws + 33554432);        //  3,145,728 B
    float*    rois = (float*)(ws + 36700160);        //  4,718,592 B
    unsigned* keys = (unsigned*)(ws + 41418752);     //  1,179,648 B
    float*    bk   = (float*)(ws + 42598400);        //    262,144 B
    unsigned* tkey = (unsigned*)(ws + 42860544);     //     65,536 B  (total ~43 MB)

    prep_wt    <<<dim3(768),      dim3(256),  0, stream>>>(wconv, wt);
    conv3x3_relu<<<dim3(2, 64, 8), dim3(128), 0, stream>>>(feat, wt, bconv, h);
    head_decode<<<dim3(64, 8),    dim3(256),  0, stream>>>(h, wsc, bsc, wlc, blc, keys, rois);
    topk_sort  <<<dim3(8),        dim3(1024), 0, stream>>>(keys, rois, bk, tkey);
    nms_out    <<<dim3(8),        dim3(256),  0, stream>>>(bk, tkey, out);
}